// Round 4
// baseline (163.480 us; speedup 1.0000x reference)
//
#include <hip/hip_runtime.h>
#include <hip/hip_bf16.h>
#include <stdint.h>

typedef __bf16 bf16;
typedef bf16 bf16x8 __attribute__((ext_vector_type(8)));
typedef float f32x4 __attribute__((ext_vector_type(4)));

#define NB   4
#define SS   2048
#define DI   1024
#define DOUT 1024

__device__ __forceinline__ void gload_lds16(const void* g, void* l) {
  __builtin_amdgcn_global_load_lds(
      (const __attribute__((address_space(1))) void*)g,
      (__attribute__((address_space(3))) void*)l, 16, 0, 0);
}

#define BARX  { __builtin_amdgcn_s_barrier(); __builtin_amdgcn_sched_barrier(0); }
#define VMW10 asm volatile("s_waitcnt vmcnt(10)" ::: "memory")
#define VMW8  asm volatile("s_waitcnt vmcnt(8)"  ::: "memory")
#define VMW4  asm volatile("s_waitcnt vmcnt(4)"  ::: "memory")
#define VMW0  asm volatile("s_waitcnt vmcnt(0)"  ::: "memory")

// ======== g256: 256x256 tile, 512 thr (8 waves 2Mx4N), counted-vmcnt ========
// LDS: 4 slots x 32KB; slot = 32-K sub-tile {A 256x32 | B 256x32}.
// Per sub-tile s: EVEN phase {stage A(s+3); vmcnt(10); bar; read B+A_lo; 16 MFMA; bar}
//                 ODD phase  {stage B(s+3); bar; read A_hi; 16 MFMA (reuse B); bar}
// Prefetch 3.5 sub-tiles ahead; loads land 5-6 phases after issue (HBM covered).
// Slot safety: sub-tile s+3 -> slot (s-1)&3, whose reads finished in pair s-1.
// Tail vmcnt: 8 / 4 / 0 for the last three sub-tiles (no staging).
// acc[FM][fn]: row = m0 + wr*128 + FM*16 + (lane>>4)*4 + rr
//              col = n0 + wcn*64 + fn*16 + (lane&15)
__device__ __forceinline__ void g256_loop(
    const bf16* __restrict__ Ag, int lda,
    const bf16* __restrict__ Bg, int ldb,
    int S, char* lds, f32x4 (&acc)[8][4])
{
  const int tid = threadIdx.x, lane = tid & 63, w = tid >> 6;
  const int wr = w >> 2, wcn = w & 3;
  const int g    = (tid & 3) ^ ((tid >> 3) & 3);
  const int srow = tid >> 2;                    // 0..127
  const int l15  = lane & 15, lg = lane >> 4;
  const int aoff = l15 * 64 + ((lg ^ ((l15 >> 1) & 3)) << 4);

  bf16x8 b[4];   // persists EVEN -> ODD

  auto STGA = [&](int t) {
    char* base = lds + (t & 3) * 32768;
#pragma unroll
    for (int j = 0; j < 2; ++j)
      gload_lds16(Ag + (size_t)(j * 128 + srow) * lda + t * 32 + g * 8,
                  base + j * 8192 + tid * 16);
  };
  auto STGB = [&](int t) {
    char* base = lds + (t & 3) * 32768 + 16384;
#pragma unroll
    for (int j = 0; j < 2; ++j)
      gload_lds16(Bg + (size_t)(j * 128 + srow) * ldb + t * 32 + g * 8,
                  base + j * 8192 + tid * 16);
  };

  auto EVEN = [&](int s, bool stg, int vmsel) {
    if (stg) STGA(s + 3);
    if (vmsel == 0) { VMW10; } else if (vmsel == 1) { VMW8; }
    else if (vmsel == 2) { VMW4; } else { VMW0; }
    BARX;
    const char* Ab = lds + (s & 3) * 32768 + wr * 8192;
    const char* Bb = lds + (s & 3) * 32768 + 16384
                     + (wcn >> 1) * 8192 + (wcn & 1) * 4096;
    bf16x8 a[4];
#pragma unroll
    for (int fn = 0; fn < 4; ++fn) b[fn] = *(const bf16x8*)(Bb + fn * 1024 + aoff);
#pragma unroll
    for (int fm = 0; fm < 4; ++fm) a[fm] = *(const bf16x8*)(Ab + fm * 1024 + aoff);
    __builtin_amdgcn_s_setprio(1);
#pragma unroll
    for (int fm = 0; fm < 4; ++fm)
#pragma unroll
      for (int fn = 0; fn < 4; ++fn)
        acc[fm][fn] = __builtin_amdgcn_mfma_f32_16x16x32_bf16(
            a[fm], b[fn], acc[fm][fn], 0, 0, 0);
    __builtin_amdgcn_s_setprio(0);
    BARX;
  };

  auto ODD = [&](int s, bool stg) {
    if (stg) STGB(s + 3);
    BARX;
    const char* Ab = lds + (s & 3) * 32768 + wr * 8192 + 4096;
    bf16x8 a[4];
#pragma unroll
    for (int fm = 0; fm < 4; ++fm) a[fm] = *(const bf16x8*)(Ab + fm * 1024 + aoff);
    __builtin_amdgcn_s_setprio(1);
#pragma unroll
    for (int fm = 0; fm < 4; ++fm)
#pragma unroll
      for (int fn = 0; fn < 4; ++fn)
        acc[4 + fm][fn] = __builtin_amdgcn_mfma_f32_16x16x32_bf16(
            a[fm], b[fn], acc[4 + fm][fn], 0, 0, 0);
    __builtin_amdgcn_s_setprio(0);
    BARX;
  };

  // prologue: sub-tiles 0,1,2 fully issued (12 loads/thread)
  STGA(0); STGB(0); STGA(1); STGB(1); STGA(2); STGB(2);

  for (int s = 0; s < S - 3; ++s) { EVEN(s, true, 0); ODD(s, true); }
  EVEN(S - 3, false, 1); ODD(S - 3, false);
  EVEN(S - 2, false, 2); ODD(S - 2, false);
  EVEN(S - 1, false, 3); ODD(S - 1, false);
}

// ------- r5h_3: 128x128 tile, BK=32, TRIPLE-buffer (16KB x3), depth-2 -------
// 4 loads/tile -> 12 in flight; vmcnt(8) retires tile t.
// acc[fm][fn]: row = m0 + wr*64 + fm*16 + (lane>>4)*4 + r;
//              col = n0 + wc*64 + fn*16 + (lane&15)
__device__ __forceinline__ void r5h_loop3(
    const bf16* __restrict__ Ag, int lda,
    const bf16* __restrict__ Bg, int ldb,
    int nt, char* lds, f32x4 (&acc)[4][4])
{
  const int tid = threadIdx.x, lane = tid & 63, wid = tid >> 6;
  const int wr = wid >> 1, wc = wid & 1;
  const int g    = (tid & 3) ^ ((tid >> 3) & 3);
  const int srow = tid >> 2;
  const int l15  = lane & 15, lg = lane >> 4;
  const int aoff = l15 * 64 + ((lg ^ ((l15 >> 1) & 3)) << 4);

  auto STG = [&](int t, int p) {
    char* Ab = lds + p * 16384;
    char* Bb = lds + p * 16384 + 8192;
#pragma unroll
    for (int i = 0; i < 2; ++i) {
      gload_lds16(Ag + (size_t)(i * 64 + srow) * lda + t * 32 + g * 8,
                  Ab + i * 4096 + tid * 16);
      gload_lds16(Bg + (size_t)(i * 64 + srow) * ldb + t * 32 + g * 8,
                  Bb + i * 4096 + tid * 16);
    }
  };

  auto CMP = [&](int p) {
    const char* Ab = lds + p * 16384 + wr * 4096;
    const char* Bb = lds + p * 16384 + 8192 + wc * 4096;
    bf16x8 a[4], bq[4];
#pragma unroll
    for (int fm = 0; fm < 4; ++fm) a[fm] = *(const bf16x8*)(Ab + fm * 1024 + aoff);
#pragma unroll
    for (int fn = 0; fn < 4; ++fn) bq[fn] = *(const bf16x8*)(Bb + fn * 1024 + aoff);
    __builtin_amdgcn_s_setprio(1);
#pragma unroll
    for (int fm = 0; fm < 4; ++fm)
#pragma unroll
      for (int fn = 0; fn < 4; ++fn)
        acc[fm][fn] = __builtin_amdgcn_mfma_f32_16x16x32_bf16(
            a[fm], bq[fn], acc[fm][fn], 0, 0, 0);
    __builtin_amdgcn_s_setprio(0);
  };

  STG(0, 0);
  STG(1, 1);
  int pw = 2, pr = 0;
  for (int t = 0; t < nt - 2; ++t) {
    STG(t + 2, pw);
    VMW8;                  // 12 in flight -> retire tile t's 4
    BARX;
    CMP(pr);
    BARX;
    pw = (pw == 2) ? 0 : pw + 1;
    pr = (pr == 2) ? 0 : pr + 1;
  }
  VMW4; BARX; CMP(pr); BARX;   // 8 in flight -> retire tile nt-2's 4
  pr = (pr == 2) ? 0 : pr + 1;
  VMW0; BARX; CMP(pr);
}

__device__ __forceinline__ void acc_zero4(f32x4 (&acc)[4][4]) {
#pragma unroll
  for (int i = 0; i < 4; ++i)
#pragma unroll
    for (int j = 0; j < 4; ++j)
      acc[i][j] = (f32x4){0.f, 0.f, 0.f, 0.f};
}

// ---------------- cast kernels ----------------

__global__ __launch_bounds__(256) void k_cast_x(const float* __restrict__ x,
                                                bf16* __restrict__ xb) {
  const size_t i = ((size_t)blockIdx.x * 256 + threadIdx.x) * 8;
  const float4 a = *(const float4*)(x + i);
  const float4 c = *(const float4*)(x + i + 4);
  bf16x8 v;
  v[0] = (bf16)a.x; v[1] = (bf16)a.y; v[2] = (bf16)a.z; v[3] = (bf16)a.w;
  v[4] = (bf16)c.x; v[5] = (bf16)c.y; v[6] = (bf16)c.z; v[7] = (bf16)c.w;
  *(bf16x8*)(xb + i) = v;
}

__global__ __launch_bounds__(256) void k_cast_wt(const float* __restrict__ Wq,
                                                 const float* __restrict__ Wk,
                                                 const float* __restrict__ Wv,
                                                 bf16* __restrict__ Wt) {
  __shared__ float t[32][33];
  const int w = blockIdx.z;
  const float* W = (w == 0) ? Wq : (w == 1) ? Wk : Wv;
  const int k0 = blockIdx.y * 32, c0 = blockIdx.x * 32;
  const int tx = threadIdx.x, ty = threadIdx.y;
#pragma unroll
  for (int i = 0; i < 4; ++i)
    t[ty + 8 * i][tx] = W[(size_t)(k0 + ty + 8 * i) * DI + c0 + tx];
  __syncthreads();
#pragma unroll
  for (int i = 0; i < 4; ++i)
    Wt[((size_t)w * DI + c0 + ty + 8 * i) * DI + k0 + tx] = (bf16)t[tx][ty + 8 * i];
}

// ------- QKV projection: 256x256 g256 tiles, 384 blocks, 512 thr, 1/CU -----
__global__ __launch_bounds__(512, 2) void k_gemm_qkv(const bf16* __restrict__ X,
                                                     const bf16* __restrict__ Wt,
                                                     bf16* __restrict__ QK,
                                                     bf16* __restrict__ VT) {
  __shared__ __align__(16) char lds[131072];   // 4 slots x 32KB
  const int bid  = blockIdx.x;
  // XCD-aware bijective swizzle: 384 = 8 * 48
  const int wgid = (bid & 7) * 48 + (bid >> 3);
  const int m0 = (wgid / 12) * 256;
  const int n0 = (wgid % 12) * 256;

  f32x4 acc[8][4];
#pragma unroll
  for (int i = 0; i < 8; ++i)
#pragma unroll
    for (int j = 0; j < 4; ++j)
      acc[i][j] = (f32x4){0.f, 0.f, 0.f, 0.f};

  g256_loop(X + (size_t)m0 * 1024, 1024, Wt + (size_t)n0 * 1024, 1024,
            32, lds, acc);

  const int lane = threadIdx.x & 63, w = threadIdx.x >> 6;
  const int wr = w >> 2, wcn = w & 3;
  const int r4 = (lane >> 4) * 4, cn = lane & 15;
  if (n0 < 2 * DOUT) {
#pragma unroll
    for (int fm = 0; fm < 8; ++fm) {
      const int row = m0 + wr * 128 + fm * 16 + r4;
#pragma unroll
      for (int fn = 0; fn < 4; ++fn) {
        const int n = n0 + wcn * 64 + fn * 16 + cn;
        const size_t base = (size_t)row * 2048 + n;
#pragma unroll
        for (int r = 0; r < 4; ++r)
          QK[base + (size_t)r * 2048] = (bf16)acc[fm][fn][r];
      }
    }
  } else {
    const int b_ = m0 >> 11;
    const int sb = (m0 & 2047) + wr * 128 + r4;
    // fn outer / fm inner: each 128B VT line completes in 8 consecutive stores
#pragma unroll
    for (int fn = 0; fn < 4; ++fn) {
      const int d = (n0 - 2 * DOUT) + wcn * 64 + fn * 16 + cn;
      bf16* vp = VT + ((size_t)b_ * DOUT + d) * SS;
#pragma unroll
      for (int fm = 0; fm < 8; ++fm) {
        const int s0 = sb + fm * 16;
        ushort4 pk;
        pk.x = __builtin_bit_cast(unsigned short, (bf16)acc[fm][fn][0]);
        pk.y = __builtin_bit_cast(unsigned short, (bf16)acc[fm][fn][1]);
        pk.z = __builtin_bit_cast(unsigned short, (bf16)acc[fm][fn][2]);
        pk.w = __builtin_bit_cast(unsigned short, (bf16)acc[fm][fn][3]);
        *(ushort4*)(vp + s0) = pk;
      }
    }
  }
}

// ---- QK^T fused exp: causal mask + exp(s*scale) + row-sum atomics ----------
// Writes unnormalized E = exp(S*scale) (0 above diagonal) and accumulates
// RS[b][q] = sum_k E. Softmax normalization deferred to PV epilogue.
// Scores are bounded (|s*scale| ~ 6), so no max-subtraction needed (f32 exp).
__global__ __launch_bounds__(256, 3) void k_gemm_qk(const bf16* __restrict__ QK,
                                                    bf16* __restrict__ E,
                                                    float* __restrict__ RS) {
  __shared__ __align__(16) char lds[49152];   // 3 x (A 8KB | B 8KB)
  const int wfl = blockIdx.x;
  const int b = wfl / 136;
  int r = wfl % 136;
  int i = 0;
  for (;;) { const int cnt = i + 1; if (r < cnt) break; r -= cnt; ++i; }
  const int m0 = i * 128, n0 = r * 128;

  const bf16* base = QK + (size_t)b * SS * 2048;
  f32x4 acc[4][4];
  acc_zero4(acc);
  r5h_loop3(base + (size_t)m0 * 2048, 2048,
            base + 1024 + (size_t)n0 * 2048, 2048, 32, lds, acc);

  bf16* Eb = E + (size_t)b * SS * SS;
  float* RSb = RS + (size_t)b * SS;
  const float scale = 0.03125f;  // 1/sqrt(1024)
  const int lane = threadIdx.x & 63, wid = threadIdx.x >> 6;
  const int wr = wid >> 1, wc = wid & 1;
  const int r4 = (lane >> 4) * 4, cn = lane & 15;

  float rsum[4][4];   // [fm][rr] partial row sums (this thread's 4 fn cols)
#pragma unroll
  for (int fm = 0; fm < 4; ++fm)
#pragma unroll
    for (int rr = 0; rr < 4; ++rr) rsum[fm][rr] = 0.f;

#pragma unroll
  for (int fm = 0; fm < 4; ++fm)
#pragma unroll
    for (int fn = 0; fn < 4; ++fn) {
      const int n = n0 + wc * 64 + fn * 16 + cn;
      const int rowb = m0 + wr * 64 + fm * 16 + r4;
      const size_t bofs = (size_t)rowb * SS + n;
#pragma unroll
      for (int rr = 0; rr < 4; ++rr) {
        const float e = (n <= rowb + rr) ? __expf(acc[fm][fn][rr] * scale) : 0.f;
        Eb[bofs + (size_t)rr * SS] = (bf16)e;
        rsum[fm][rr] += e;
      }
    }

  // reduce over the 16 cn-lanes (same row group: lane>>4 invariant under xor<16)
#pragma unroll
  for (int fm = 0; fm < 4; ++fm)
#pragma unroll
    for (int rr = 0; rr < 4; ++rr) {
      float s = rsum[fm][rr];
      s += __shfl_xor(s, 1);
      s += __shfl_xor(s, 2);
      s += __shfl_xor(s, 4);
      s += __shfl_xor(s, 8);
      if (cn == 0)
        atomicAdd(&RSb[m0 + wr * 64 + fm * 16 + r4 + rr], s);
    }
}

// ---------------- PV: r5h3, anti-correlated balance (512 blocks) ------------
// Consumes unnormalized E; divides by RS[row] in epilogue.
__global__ __launch_bounds__(256, 3) void k_gemm_pv(const bf16* __restrict__ P,
                                                    const bf16* __restrict__ VT,
                                                    const float* __restrict__ RS,
                                                    float* __restrict__ Out) {
  __shared__ __align__(16) char lds[49152];
  const int wfl = blockIdx.x;
  const int h = wfl >> 8;
  const int r = wfl & 255;
  const int b = r >> 6;
  const int t = r & 63;
  const int ip = t >> 3;
  const int j = t & 7;
  const int i = h ? (15 - ip) : ip;
  const int m0 = i * 128, n0 = j * 128;
  const int nt = 4 * (i + 1);     // s-tiles [0, (i+1)*128)

  f32x4 acc[4][4];
  acc_zero4(acc);
  r5h_loop3(P  + (size_t)b * SS * SS   + (size_t)m0 * SS, SS,
            VT + (size_t)b * DOUT * SS + (size_t)n0 * SS, SS,
            nt, lds, acc);

  float* Ob = Out + (size_t)b * SS * DOUT;
  const float* RSb = RS + (size_t)b * SS;
  const int lane = threadIdx.x & 63, wid = threadIdx.x >> 6;
  const int wr = wid >> 1, wc = wid & 1;
  const int r4 = (lane >> 4) * 4, cn = lane & 15;
#pragma unroll
  for (int fm = 0; fm < 4; ++fm) {
    const int rowb = m0 + wr * 64 + fm * 16 + r4;
    const float4 rs4 = *(const float4*)(RSb + rowb);
    float inv[4];
    inv[0] = 1.0f / rs4.x; inv[1] = 1.0f / rs4.y;
    inv[2] = 1.0f / rs4.z; inv[3] = 1.0f / rs4.w;
#pragma unroll
    for (int fn = 0; fn < 4; ++fn) {
      const int n = n0 + wc * 64 + fn * 16 + cn;
      const size_t bofs = (size_t)rowb * DOUT + n;
#pragma unroll
      for (int rr = 0; rr < 4; ++rr)
        Ob[bofs + (size_t)rr * DOUT] = acc[fm][fn][rr] * inv[rr];
    }
  }
}

// ---------------- launch ----------------
extern "C" void kernel_launch(void* const* d_in, const int* in_sizes, int n_in,
                              void* d_out, int out_size, void* d_ws, size_t ws_size,
                              hipStream_t stream) {
  const float* x  = (const float*)d_in[0];
  const float* Wq = (const float*)d_in[1];
  const float* Wk = (const float*)d_in[2];
  const float* Wv = (const float*)d_in[3];
  float* out = (float*)d_out;
  char* ws = (char*)d_ws;

  bf16*  QK = (bf16*)(ws);                        // 32 MB [8192][2048]
  bf16*  VT = (bf16*)(ws + ((size_t)32 << 20));   // 16 MB [4][1024][2048]
  bf16*  E  = (bf16*)(ws + ((size_t)48 << 20));   // 32 MB unnormalized exp scores
  bf16*  XB = (bf16*)(ws + ((size_t)48 << 20));   // 16 MB (overlaps E; dead before qk)
  bf16*  WT = (bf16*)(ws + ((size_t)64 << 20));   //  6 MB (overlaps E; dead before qk)
  float* RS = (float*)(ws + ((size_t)80 << 20));  // 32 KB row sums [4][2048]

  hipMemsetAsync(RS, 0, (size_t)NB * SS * sizeof(float), stream);
  k_cast_x<<<4096, 256, 0, stream>>>(x, XB);
  k_cast_wt<<<dim3(32, 32, 3), dim3(32, 8), 0, stream>>>(Wq, Wk, Wv, WT);
  k_gemm_qkv<<<384, 512, 0, stream>>>(XB, WT, QK, VT);
  k_gemm_qk<<<544, 256, 0, stream>>>(QK, E, RS);
  k_gemm_pv<<<512, 256, 0, stream>>>(E, VT, RS, out);
}

// Round 5
// 144.244 us; speedup vs baseline: 1.1334x; 1.1334x over previous
//
#include <hip/hip_runtime.h>
#include <hip/hip_bf16.h>
#include <stdint.h>

typedef __bf16 bf16;
typedef bf16 bf16x8 __attribute__((ext_vector_type(8)));
typedef float f32x4 __attribute__((ext_vector_type(4)));

#define NB   4
#define SS   2048
#define DI   1024
#define DOUT 1024

__device__ __forceinline__ void gload_lds16(const void* g, void* l) {
  __builtin_amdgcn_global_load_lds(
      (const __attribute__((address_space(1))) void*)g,
      (__attribute__((address_space(3))) void*)l, 16, 0, 0);
}

#define BARX  { __builtin_amdgcn_s_barrier(); __builtin_amdgcn_sched_barrier(0); }
#define VMW12 asm volatile("s_waitcnt vmcnt(12)" ::: "memory")
#define VMW8  asm volatile("s_waitcnt vmcnt(8)"  ::: "memory")
#define VMW6  asm volatile("s_waitcnt vmcnt(6)"  ::: "memory")
#define VMW4  asm volatile("s_waitcnt vmcnt(4)"  ::: "memory")
#define VMW0  asm volatile("s_waitcnt vmcnt(0)"  ::: "memory")

// ------- r5_3: 128x256 tile, BK=32, TRIPLE-buffer (24KB x3), depth-2 --------
// 6 loads/tile -> 18 in flight; vmcnt(12) retires tile t.
// acc[am][fn]: row = m0 + am*16 + (lane>>4)*4 + r; col = n0 + w*64 + fn*16 + (lane&15)
__device__ __forceinline__ void r5_loop3(
    const bf16* __restrict__ Ag, int lda,
    const bf16* __restrict__ Bg, int ldb,
    int nt, char* lds, f32x4 (&acc)[8][4])
{
  const int tid = threadIdx.x, lane = tid & 63, w = tid >> 6;
  const int g    = (tid & 3) ^ ((tid >> 3) & 3);
  const int srow = tid >> 2;
  const int l15  = lane & 15, lg = lane >> 4;
  const int aoff = l15 * 64 + ((lg ^ ((l15 >> 1) & 3)) << 4);

  auto STG = [&](int t, int p) {
    char* Ab = lds + p * 24576;
    char* Bb = lds + p * 24576 + 8192;
#pragma unroll
    for (int i = 0; i < 2; ++i)
      gload_lds16(Ag + (size_t)(i * 64 + srow) * lda + t * 32 + g * 8,
                  Ab + i * 4096 + tid * 16);
#pragma unroll
    for (int i = 0; i < 4; ++i)
      gload_lds16(Bg + (size_t)(i * 64 + srow) * ldb + t * 32 + g * 8,
                  Bb + i * 4096 + tid * 16);
  };

  auto CMP = [&](int p) {
    const char* Ab = lds + p * 24576;
    const char* Bb = lds + p * 24576 + 8192 + w * 4096;
    bf16x8 a[8], bq[4];
#pragma unroll
    for (int am = 0; am < 8; ++am) a[am] = *(const bf16x8*)(Ab + am * 1024 + aoff);
#pragma unroll
    for (int fn = 0; fn < 4; ++fn) bq[fn] = *(const bf16x8*)(Bb + fn * 1024 + aoff);
    __builtin_amdgcn_s_setprio(1);
#pragma unroll
    for (int am = 0; am < 8; ++am)
#pragma unroll
      for (int fn = 0; fn < 4; ++fn)
        acc[am][fn] = __builtin_amdgcn_mfma_f32_16x16x32_bf16(
            a[am], bq[fn], acc[am][fn], 0, 0, 0);
    __builtin_amdgcn_s_setprio(0);
  };

  STG(0, 0);
  STG(1, 1);
  int pw = 2, pr = 0;
  for (int t = 0; t < nt - 2; ++t) {
    STG(t + 2, pw);
    VMW12;                 // 18 in flight -> retire tile t's 6
    BARX;
    CMP(pr);
    BARX;
    pw = (pw == 2) ? 0 : pw + 1;
    pr = (pr == 2) ? 0 : pr + 1;
  }
  VMW6; BARX; CMP(pr); BARX;   // 12 in flight -> retire tile nt-2's 6
  pr = (pr == 2) ? 0 : pr + 1;
  VMW0; BARX; CMP(pr);
}

// ------- r5h_3: 128x128 tile, BK=32, TRIPLE-buffer (16KB x3), depth-2 -------
// 4 loads/tile -> 12 in flight; vmcnt(8) retires tile t.
// acc[fm][fn]: row = m0 + wr*64 + fm*16 + (lane>>4)*4 + r;
//              col = n0 + wc*64 + fn*16 + (lane&15)
__device__ __forceinline__ void r5h_loop3(
    const bf16* __restrict__ Ag, int lda,
    const bf16* __restrict__ Bg, int ldb,
    int nt, char* lds, f32x4 (&acc)[4][4])
{
  const int tid = threadIdx.x, lane = tid & 63, wid = tid >> 6;
  const int wr = wid >> 1, wc = wid & 1;
  const int g    = (tid & 3) ^ ((tid >> 3) & 3);
  const int srow = tid >> 2;
  const int l15  = lane & 15, lg = lane >> 4;
  const int aoff = l15 * 64 + ((lg ^ ((l15 >> 1) & 3)) << 4);

  auto STG = [&](int t, int p) {
    char* Ab = lds + p * 16384;
    char* Bb = lds + p * 16384 + 8192;
#pragma unroll
    for (int i = 0; i < 2; ++i) {
      gload_lds16(Ag + (size_t)(i * 64 + srow) * lda + t * 32 + g * 8,
                  Ab + i * 4096 + tid * 16);
      gload_lds16(Bg + (size_t)(i * 64 + srow) * ldb + t * 32 + g * 8,
                  Bb + i * 4096 + tid * 16);
    }
  };

  auto CMP = [&](int p) {
    const char* Ab = lds + p * 16384 + wr * 4096;
    const char* Bb = lds + p * 16384 + 8192 + wc * 4096;
    bf16x8 a[4], bq[4];
#pragma unroll
    for (int fm = 0; fm < 4; ++fm) a[fm] = *(const bf16x8*)(Ab + fm * 1024 + aoff);
#pragma unroll
    for (int fn = 0; fn < 4; ++fn) bq[fn] = *(const bf16x8*)(Bb + fn * 1024 + aoff);
    __builtin_amdgcn_s_setprio(1);
#pragma unroll
    for (int fm = 0; fm < 4; ++fm)
#pragma unroll
      for (int fn = 0; fn < 4; ++fn)
        acc[fm][fn] = __builtin_amdgcn_mfma_f32_16x16x32_bf16(
            a[fm], bq[fn], acc[fm][fn], 0, 0, 0);
    __builtin_amdgcn_s_setprio(0);
  };

  STG(0, 0);
  STG(1, 1);
  int pw = 2, pr = 0;
  for (int t = 0; t < nt - 2; ++t) {
    STG(t + 2, pw);
    VMW8;                  // 12 in flight -> retire tile t's 4
    BARX;
    CMP(pr);
    BARX;
    pw = (pw == 2) ? 0 : pw + 1;
    pr = (pr == 2) ? 0 : pr + 1;
  }
  VMW4; BARX; CMP(pr); BARX;   // 8 in flight -> retire tile nt-2's 4
  pr = (pr == 2) ? 0 : pr + 1;
  VMW0; BARX; CMP(pr);
}

__device__ __forceinline__ void acc_zero4(f32x4 (&acc)[4][4]) {
#pragma unroll
  for (int i = 0; i < 4; ++i)
#pragma unroll
    for (int j = 0; j < 4; ++j)
      acc[i][j] = (f32x4){0.f, 0.f, 0.f, 0.f};
}

// ---------------- weight cast: straight bf16 for Wq,Wk; transposed for Wv ----
__global__ __launch_bounds__(256) void k_cast_wt(const float* __restrict__ Wq,
                                                 const float* __restrict__ Wk,
                                                 const float* __restrict__ Wv,
                                                 bf16* __restrict__ WSq,
                                                 bf16* __restrict__ WSk,
                                                 bf16* __restrict__ WTv) {
  __shared__ float t[32][33];
  const int w = blockIdx.z;
  const int k0 = blockIdx.y * 32, c0 = blockIdx.x * 32;
  const int tx = threadIdx.x, ty = threadIdx.y;
  if (w < 2) {
    const float* W = w ? Wk : Wq;
    bf16* WS = w ? WSk : WSq;
#pragma unroll
    for (int i = 0; i < 4; ++i) {
      const size_t idx = (size_t)(k0 + ty + 8 * i) * DI + c0 + tx;
      WS[idx] = (bf16)W[idx];
    }
  } else {
#pragma unroll
    for (int i = 0; i < 4; ++i)
      t[ty + 8 * i][tx] = Wv[(size_t)(k0 + ty + 8 * i) * DI + c0 + tx];
    __syncthreads();
#pragma unroll
    for (int i = 0; i < 4; ++i)
      WTv[(size_t)(c0 + ty + 8 * i) * DI + k0 + tx] = (bf16)t[tx][ty + 8 * i];
  }
}

// ---- x-cast + MT = Wk.Wq^T (M^T) fused in one dispatch --------------------
// Blocks [0,64): MT tiles (r5h, 128x128); blocks [64,4160): vectorized x cast.
// MT[j'][j] = sum_d Wk[j'][d]*Wq[j][d]  (so scores = (X.MT^T... ) = X*M*X^T)
__global__ __launch_bounds__(256) void k_castx_mt(const float* __restrict__ x,
                                                  bf16* __restrict__ xb,
                                                  const bf16* __restrict__ WSk,
                                                  const bf16* __restrict__ WSq,
                                                  bf16* __restrict__ MT) {
  __shared__ __align__(16) char lds[49152];
  const int bid = blockIdx.x;
  if (bid < 64) {
    const int m0 = (bid >> 3) * 128, n0 = (bid & 7) * 128;
    f32x4 acc[4][4];
    acc_zero4(acc);
    r5h_loop3(WSk + (size_t)m0 * 1024, 1024, WSq + (size_t)n0 * 1024, 1024,
              32, lds, acc);
    const int lane = threadIdx.x & 63, wid = threadIdx.x >> 6;
    const int wr = wid >> 1, wc = wid & 1;
    const int r4 = (lane >> 4) * 4, cn = lane & 15;
#pragma unroll
    for (int fm = 0; fm < 4; ++fm)
#pragma unroll
      for (int fn = 0; fn < 4; ++fn) {
        const int row = m0 + wr * 64 + fm * 16 + r4;
        const int col = n0 + wc * 64 + fn * 16 + cn;
#pragma unroll
        for (int rr = 0; rr < 4; ++rr)
          MT[(size_t)(row + rr) * 1024 + col] = (bf16)acc[fm][fn][rr];
      }
  } else {
    const size_t i = ((size_t)(bid - 64) * 256 + threadIdx.x) * 8;
    const float4 a = *(const float4*)(x + i);
    const float4 c = *(const float4*)(x + i + 4);
    bf16x8 v;
    v[0] = (bf16)a.x; v[1] = (bf16)a.y; v[2] = (bf16)a.z; v[3] = (bf16)a.w;
    v[4] = (bf16)c.x; v[5] = (bf16)c.y; v[6] = (bf16)c.z; v[7] = (bf16)c.w;
    *(bf16x8*)(xb + i) = v;
  }
}

// ------- T|V fused: 128x256 r5 tiles, 512 blocks, 2 blk/CU, 1.0 rounds ------
// n0 < 1024: T = X*M (row-major, B-operand = MT);  n0 >= 1024: V (stored V^T).
__global__ __launch_bounds__(256, 2) void k_tv(const bf16* __restrict__ X,
                                               const bf16* __restrict__ MT,
                                               const bf16* __restrict__ WTv,
                                               bf16* __restrict__ T,
                                               bf16* __restrict__ VT) {
  __shared__ __align__(16) char lds[73728];   // 3 x (A 8KB | B 16KB)
  const int bid  = blockIdx.x;
  // XCD-aware bijective swizzle: 512 = 8 * 64
  const int wgid = (bid & 7) * 64 + (bid >> 3);
  const int m0 = (wgid >> 3) * 128;
  const int n0 = (wgid & 7) * 256;

  const bf16* Bg = (n0 < 1024) ? MT + (size_t)n0 * 1024
                               : WTv + (size_t)(n0 - 1024) * 1024;

  f32x4 acc[8][4];
#pragma unroll
  for (int i = 0; i < 8; ++i)
#pragma unroll
    for (int j = 0; j < 4; ++j)
      acc[i][j] = (f32x4){0.f, 0.f, 0.f, 0.f};

  r5_loop3(X + (size_t)m0 * 1024, 1024, Bg, 1024, 32, lds, acc);

  const int lane = threadIdx.x & 63, w = threadIdx.x >> 6;
  const int r4 = (lane >> 4) * 4;
  const int cn = lane & 15;
  if (n0 < 1024) {
#pragma unroll
    for (int am = 0; am < 8; ++am) {
      const int row = m0 + am * 16 + r4;
#pragma unroll
      for (int fn = 0; fn < 4; ++fn) {
        const int n = n0 + w * 64 + fn * 16 + cn;
        const size_t base = (size_t)row * 1024 + n;
#pragma unroll
        for (int r = 0; r < 4; ++r)
          T[base + (size_t)r * 1024] = (bf16)acc[am][fn][r];
      }
    }
  } else {
    const int b_ = m0 >> 11;
    const int sb = m0 & 2047;
#pragma unroll
    for (int am = 0; am < 8; ++am)
#pragma unroll
      for (int fn = 0; fn < 4; ++fn) {
        const int d  = (n0 - 1024) + w * 64 + fn * 16 + cn;
        const int s0 = sb + am * 16 + r4;
        ushort4 pk;
        pk.x = __builtin_bit_cast(unsigned short, (bf16)acc[am][fn][0]);
        pk.y = __builtin_bit_cast(unsigned short, (bf16)acc[am][fn][1]);
        pk.z = __builtin_bit_cast(unsigned short, (bf16)acc[am][fn][2]);
        pk.w = __builtin_bit_cast(unsigned short, (bf16)acc[am][fn][3]);
        *(ushort4*)(VT + ((size_t)b_ * DOUT + d) * SS + s0) = pk;
      }
  }
}

// ---- scores = T.X^T, fused exp: causal mask + exp(s*scale) + row-sum -------
// Writes unnormalized E = exp(S*scale) (0 above diagonal) and accumulates
// RS[b][q] = sum_k E. Softmax normalization deferred to PV epilogue.
__global__ __launch_bounds__(256, 3) void k_gemm_qk(const bf16* __restrict__ T,
                                                    const bf16* __restrict__ XB,
                                                    bf16* __restrict__ E,
                                                    float* __restrict__ RS) {
  __shared__ __align__(16) char lds[49152];   // 3 x (A 8KB | B 8KB)
  const int wfl = blockIdx.x;
  const int b = wfl / 136;
  int r = wfl % 136;
  int i = 0;
  for (;;) { const int cnt = i + 1; if (r < cnt) break; r -= cnt; ++i; }
  const int m0 = i * 128, n0 = r * 128;

  f32x4 acc[4][4];
  acc_zero4(acc);
  r5h_loop3(T  + ((size_t)b * SS + m0) * 1024, 1024,
            XB + ((size_t)b * SS + n0) * 1024, 1024, 32, lds, acc);

  bf16* Eb = E + (size_t)b * SS * SS;
  float* RSb = RS + (size_t)b * SS;
  const float scale = 0.03125f;  // 1/sqrt(1024)
  const int lane = threadIdx.x & 63, wid = threadIdx.x >> 6;
  const int wr = wid >> 1, wc = wid & 1;
  const int r4 = (lane >> 4) * 4, cn = lane & 15;

  float rsum[4][4];   // [fm][rr] partial row sums (this thread's 4 fn cols)
#pragma unroll
  for (int fm = 0; fm < 4; ++fm)
#pragma unroll
    for (int rr = 0; rr < 4; ++rr) rsum[fm][rr] = 0.f;

#pragma unroll
  for (int fm = 0; fm < 4; ++fm)
#pragma unroll
    for (int fn = 0; fn < 4; ++fn) {
      const int n = n0 + wc * 64 + fn * 16 + cn;
      const int rowb = m0 + wr * 64 + fm * 16 + r4;
      const size_t bofs = (size_t)rowb * SS + n;
#pragma unroll
      for (int rr = 0; rr < 4; ++rr) {
        const float e = (n <= rowb + rr) ? __expf(acc[fm][fn][rr] * scale) : 0.f;
        Eb[bofs + (size_t)rr * SS] = (bf16)e;
        rsum[fm][rr] += e;
      }
    }

  // reduce over the 16 cn-lanes (same row group: lane>>4 invariant under xor<16)
#pragma unroll
  for (int fm = 0; fm < 4; ++fm)
#pragma unroll
    for (int rr = 0; rr < 4; ++rr) {
      float s = rsum[fm][rr];
      s += __shfl_xor(s, 1);
      s += __shfl_xor(s, 2);
      s += __shfl_xor(s, 4);
      s += __shfl_xor(s, 8);
      if (cn == 0)
        atomicAdd(&RSb[m0 + wr * 64 + fm * 16 + r4 + rr], s);
    }
}

// ---------------- PV: r5h3, anti-correlated balance (512 blocks) ------------
// Consumes unnormalized E; divides by RS[row] in epilogue.
__global__ __launch_bounds__(256, 3) void k_gemm_pv(const bf16* __restrict__ P,
                                                    const bf16* __restrict__ VT,
                                                    const float* __restrict__ RS,
                                                    float* __restrict__ Out) {
  __shared__ __align__(16) char lds[49152];
  const int wfl = blockIdx.x;
  const int h = wfl >> 8;
  const int r = wfl & 255;
  const int b = r >> 6;
  const int t = r & 63;
  const int ip = t >> 3;
  const int j = t & 7;
  const int i = h ? (15 - ip) : ip;
  const int m0 = i * 128, n0 = j * 128;
  const int nt = 4 * (i + 1);     // s-tiles [0, (i+1)*128)

  f32x4 acc[4][4];
  acc_zero4(acc);
  r5h_loop3(P  + (size_t)b * SS * SS   + (size_t)m0 * SS, SS,
            VT + (size_t)b * DOUT * SS + (size_t)n0 * SS, SS,
            nt, lds, acc);

  float* Ob = Out + (size_t)b * SS * DOUT;
  const float* RSb = RS + (size_t)b * SS;
  const int lane = threadIdx.x & 63, wid = threadIdx.x >> 6;
  const int wr = wid >> 1, wc = wid & 1;
  const int r4 = (lane >> 4) * 4, cn = lane & 15;
#pragma unroll
  for (int fm = 0; fm < 4; ++fm) {
    const int rowb = m0 + wr * 64 + fm * 16 + r4;
    const float4 rs4 = *(const float4*)(RSb + rowb);
    float inv[4];
    inv[0] = 1.0f / rs4.x; inv[1] = 1.0f / rs4.y;
    inv[2] = 1.0f / rs4.z; inv[3] = 1.0f / rs4.w;
#pragma unroll
    for (int fn = 0; fn < 4; ++fn) {
      const int n = n0 + wc * 64 + fn * 16 + cn;
      const size_t bofs = (size_t)rowb * DOUT + n;
#pragma unroll
      for (int rr = 0; rr < 4; ++rr)
        Ob[bofs + (size_t)rr * DOUT] = acc[fm][fn][rr] * inv[rr];
    }
  }
}

// ---------------- launch ----------------
extern "C" void kernel_launch(void* const* d_in, const int* in_sizes, int n_in,
                              void* d_out, int out_size, void* d_ws, size_t ws_size,
                              hipStream_t stream) {
  const float* x  = (const float*)d_in[0];
  const float* Wq = (const float*)d_in[1];
  const float* Wk = (const float*)d_in[2];
  const float* Wv = (const float*)d_in[3];
  float* out = (float*)d_out;
  char* ws = (char*)d_ws;

  bf16*  T   = (bf16*)(ws);                        // 16 MB [8192][1024]  X*M
  bf16*  VT  = (bf16*)(ws + ((size_t)16 << 20));   // 16 MB [4][1024][2048]
  bf16*  E   = (bf16*)(ws + ((size_t)32 << 20));   // 32 MB unnormalized exp scores
  bf16*  XB  = (bf16*)(ws + ((size_t)64 << 20));   // 16 MB (live through qk!)
  bf16*  WSq = (bf16*)(ws + ((size_t)80 << 20));   //  2 MB straight bf16 Wq
  bf16*  WSk = (bf16*)(ws + ((size_t)82 << 20));   //  2 MB straight bf16 Wk
  bf16*  WTv = (bf16*)(ws + ((size_t)84 << 20));   //  2 MB transposed bf16 Wv
  bf16*  MT  = (bf16*)(ws + ((size_t)86 << 20));   //  2 MB M^T = Wk.Wq^T
  float* RS  = (float*)(ws + ((size_t)88 << 20));  // 32 KB row sums [4][2048]

  hipMemsetAsync(RS, 0, (size_t)NB * SS * sizeof(float), stream);
  k_cast_wt<<<dim3(32, 32, 3), dim3(32, 8), 0, stream>>>(Wq, Wk, Wv, WSq, WSk, WTv);
  k_castx_mt<<<4160, 256, 0, stream>>>(x, XB, WSk, WSq, MT);
  k_tv<<<512, 256, 0, stream>>>(XB, MT, WTv, T, VT);
  k_gemm_qk<<<544, 256, 0, stream>>>(T, XB, E, RS);
  k_gemm_pv<<<512, 256, 0, stream>>>(E, VT, RS, out);
}